// Round 1
// baseline (140.288 us; speedup 1.0000x reference)
//
#include <hip/hip_runtime.h>
#include <math.h>

#define VOCAB  30522
#define HIDDEN 768
#define EMB    128
#define BATCH  1024
#define QLEN   32
#define DLEN   180
#define NEGV   (-1e4f)

// ---------------------------------------------------------------------------
// Kernel 1: pe[v][d] = normalize(embed_table[v] @ W + b)   (v < VOCAB, d < 128)
// block = 256 threads, 32 vocab rows per block; thread = 4 rows x 4 cols.
// LDS: W k-chunk [64][128] (32 KB) + emb rows [32][64] (8 KB) = 40 KB.
// ---------------------------------------------------------------------------
__global__ __launch_bounds__(256) void colbert_proj(
    const float* __restrict__ emb, const float* __restrict__ W,
    const float* __restrict__ bias, float* __restrict__ pe) {
  __shared__ float4 Wt4[64 * 32];  // [h=64][d=128] as float4 slots [h][32]
  __shared__ float4 Et4[32 * 16];  // [row=32][h=64] as float4 slots [row][16]

  const int tid  = threadIdx.x;
  const int tc   = tid & 31;   // d-quad: cols tc*4 .. tc*4+3
  const int tr   = tid >> 5;   // row group: rows tr*4 .. tr*4+3
  const int row0 = blockIdx.x * 32;

  float4 acc[4];
#pragma unroll
  for (int r = 0; r < 4; ++r) acc[r] = make_float4(0.f, 0.f, 0.f, 0.f);

  for (int hc = 0; hc < HIDDEN / 64; ++hc) {
    __syncthreads();  // protect previous chunk's reads
    // stage W chunk: contiguous 64*128 floats = 2048 float4
    const float4* Wg4 = (const float4*)(W + hc * 64 * EMB);
#pragma unroll
    for (int i = 0; i < 8; ++i) {
      int idx = i * 256 + tid;
      Wt4[idx] = Wg4[idx];
    }
    // stage emb rows: 32 rows x 64 floats = 512 float4
#pragma unroll
    for (int i = 0; i < 2; ++i) {
      int idx = i * 256 + tid;           // < 512
      int r = idx >> 4, c4 = idx & 15;
      int vr = row0 + r;
      if (vr >= VOCAB) vr = VOCAB - 1;   // clamp (store is guarded)
      Et4[idx] = ((const float4*)(emb + (size_t)vr * HIDDEN + hc * 64))[c4];
    }
    __syncthreads();

#pragma unroll
    for (int k4 = 0; k4 < 16; ++k4) {
      float4 w0 = Wt4[(k4 * 4 + 0) * 32 + tc];
      float4 w1 = Wt4[(k4 * 4 + 1) * 32 + tc];
      float4 w2 = Wt4[(k4 * 4 + 2) * 32 + tc];
      float4 w3 = Wt4[(k4 * 4 + 3) * 32 + tc];
#pragma unroll
      for (int r = 0; r < 4; ++r) {
        float4 e = Et4[(tr * 4 + r) * 16 + k4];
        acc[r].x += e.x * w0.x; acc[r].y += e.x * w0.y; acc[r].z += e.x * w0.z; acc[r].w += e.x * w0.w;
        acc[r].x += e.y * w1.x; acc[r].y += e.y * w1.y; acc[r].z += e.y * w1.z; acc[r].w += e.y * w1.w;
        acc[r].x += e.z * w2.x; acc[r].y += e.z * w2.y; acc[r].z += e.z * w2.z; acc[r].w += e.z * w2.w;
        acc[r].x += e.w * w3.x; acc[r].y += e.w * w3.y; acc[r].z += e.w * w3.z; acc[r].w += e.w * w3.w;
      }
    }
  }

  // bias + L2-normalize (row is spread over 32 lanes: same tr = one 32-lane half)
  float4 bv = ((const float4*)bias)[tc];
#pragma unroll
  for (int r = 0; r < 4; ++r) {
    acc[r].x += bv.x; acc[r].y += bv.y; acc[r].z += bv.z; acc[r].w += bv.w;
    float ss = acc[r].x * acc[r].x + acc[r].y * acc[r].y +
               acc[r].z * acc[r].z + acc[r].w * acc[r].w;
#pragma unroll
    for (int m = 16; m >= 1; m >>= 1) ss += __shfl_xor(ss, m);
    float scale = 1.f / (sqrtf(ss) + 1e-12f);
    int vr = row0 + tr * 4 + r;
    if (vr < VOCAB) {
      float4 o = make_float4(acc[r].x * scale, acc[r].y * scale,
                             acc[r].z * scale, acc[r].w * scale);
      ((float4*)pe)[(size_t)vr * 32 + tc] = o;
    }
  }
}

// ---------------------------------------------------------------------------
// Kernel 2: per-batch MaxSim score.
// block = 256 threads, one batch each. q staged in LDS (16 KB); doc tokens in
// 3 tiles of 64 rows (32 KB), float4 slots rotation-swizzled: phys = (k4+t)&31
// so stride-512B column reads are bank-conflict-free.
// thread (tq = tid>>5, tc = tid&31): 4 q-rows x 2 doc-slots per tile.
// ---------------------------------------------------------------------------
__global__ __launch_bounds__(256) void colbert_score(
    const int* __restrict__ qids, const int* __restrict__ qmask,
    const int* __restrict__ dids, const int* __restrict__ dmask,
    const float* __restrict__ pe, float* __restrict__ out) {
  __shared__ float4 qs4[32 * 32];  // [q=32][k4=32]  16 KB
  __shared__ float4 ds4[64 * 32];  // [t=64][slot=32] 32 KB (swizzled)
  __shared__ float partial[8];

  const int b   = blockIdx.x;
  const int tid = threadIdx.x;
  const int tc  = tid & 31;
  const int tq  = tid >> 5;  // 0..7 -> q rows tq*4 .. tq*4+3

  // stage all 32 query embeddings
#pragma unroll
  for (int i = 0; i < 4; ++i) {
    int idx = i * 256 + tid;           // < 1024
    int qrow = idx >> 5, c4 = idx & 31;
    int qid = qids[b * QLEN + qrow];
    qs4[idx] = ((const float4*)pe)[(size_t)qid * 32 + c4];
  }

  float maxv[4] = {-3.0e38f, -3.0e38f, -3.0e38f, -3.0e38f};

  for (int tile = 0; tile < 3; ++tile) {
    __syncthreads();  // protect qs4 writes (tile 0) / previous ds4 reads
    // stage 64 doc rows: 2048 float4, rotation-swizzled slots
#pragma unroll
    for (int i = 0; i < 8; ++i) {
      int idx = i * 256 + tid;         // < 2048
      int tl = idx >> 5, c4 = idx & 31;
      int t = tile * 64 + tl;
      int did = dids[b * DLEN + (t < DLEN ? t : DLEN - 1)];
      ds4[tl * 32 + ((c4 + tl) & 31)] = ((const float4*)pe)[(size_t)did * 32 + c4];
    }
    __syncthreads();

    float dots[2][4];
#pragma unroll
    for (int j = 0; j < 2; ++j)
#pragma unroll
      for (int r = 0; r < 4; ++r) dots[j][r] = 0.f;

#pragma unroll 4
    for (int k4 = 0; k4 < 32; ++k4) {
      int slot = (k4 + tc) & 31;                  // same for tc and tc+32
      float4 d0 = ds4[tc * 32 + slot];
      float4 d1 = ds4[(tc + 32) * 32 + slot];
#pragma unroll
      for (int r = 0; r < 4; ++r) {
        float4 q = qs4[(tq * 4 + r) * 32 + k4];
        dots[0][r] += q.x * d0.x + q.y * d0.y + q.z * d0.z + q.w * d0.w;
        dots[1][r] += q.x * d1.x + q.y * d1.y + q.z * d1.z + q.w * d1.w;
      }
    }

#pragma unroll
    for (int j = 0; j < 2; ++j) {
      int t = tile * 64 + tc + 32 * j;
      if (t < DLEN) {
        int m = dmask[b * DLEN + t];
#pragma unroll
        for (int r = 0; r < 4; ++r) {
          float s = (m > 0) ? dots[j][r] : NEGV;
          maxv[r] = fmaxf(maxv[r], s);
        }
      }
    }
  }

  // reduce max over the 32 tc-lanes (tq constant within each 32-lane half)
#pragma unroll
  for (int r = 0; r < 4; ++r) {
#pragma unroll
    for (int m = 16; m >= 1; m >>= 1)
      maxv[r] = fmaxf(maxv[r], __shfl_xor(maxv[r], m));
  }

  if (tc == 0) {
    float s = 0.f;
#pragma unroll
    for (int r = 0; r < 4; ++r)
      s += maxv[r] * (float)qmask[b * QLEN + tq * 4 + r];
    partial[tq] = s;
  }
  __syncthreads();
  if (tid == 0) {
    float s = 0.f;
#pragma unroll
    for (int i = 0; i < 8; ++i) s += partial[i];
    out[b] = s;
  }
}

// ---------------------------------------------------------------------------
extern "C" void kernel_launch(void* const* d_in, const int* in_sizes, int n_in,
                              void* d_out, int out_size, void* d_ws, size_t ws_size,
                              hipStream_t stream) {
  const int*   qids  = (const int*)d_in[0];
  const int*   qmask = (const int*)d_in[1];
  const int*   dids  = (const int*)d_in[2];
  const int*   dmask = (const int*)d_in[3];
  const float* emb   = (const float*)d_in[4];
  const float* W     = (const float*)d_in[5];
  const float* bias  = (const float*)d_in[6];
  float*       out   = (float*)d_out;
  float*       pe    = (float*)d_ws;  // VOCAB*128 fp32 = 15.6 MB

  int proj_blocks = (VOCAB + 31) / 32;  // 954
  colbert_proj<<<proj_blocks, 256, 0, stream>>>(emb, W, bias, pe);
  colbert_score<<<BATCH, 256, 0, stream>>>(qids, qmask, dids, dmask, pe, out);
}

// Round 2
// 83.224 us; speedup vs baseline: 1.6857x; 1.6857x over previous
//
#include <hip/hip_runtime.h>
#include <math.h>

#define VOCAB  30522
#define HIDDEN 768
#define EMB    128
#define BATCH  1024
#define QLEN   32
#define DLEN   180
#define NEGV   (-1e4f)

typedef __attribute__((ext_vector_type(8))) short bf16x8;
typedef __attribute__((ext_vector_type(4))) float f32x4;

__device__ __forceinline__ unsigned short f2bf(float x) {
  union { float f; unsigned u; } v; v.f = x;
  unsigned r = v.u + 0x7FFFu + ((v.u >> 16) & 1u);
  return (unsigned short)(r >> 16);
}
__device__ __forceinline__ float bf2f(unsigned short h) {
  union { float f; unsigned u; } v; v.u = ((unsigned)h) << 16;
  return v.f;
}

// ---------------------------------------------------------------------------
// Kernel 0: W [768][128] fp32  ->  WT_hi / WT_lo  bf16 [128][768] (split).
// ---------------------------------------------------------------------------
__global__ __launch_bounds__(256) void prep_wt(
    const float* __restrict__ W, unsigned short* __restrict__ wth,
    unsigned short* __restrict__ wtl) {
  __shared__ float tile[32][33];
  const int k0 = blockIdx.x * 32, n0 = blockIdx.y * 32;
  const int t = threadIdx.x, r = t >> 5, c = t & 31;
#pragma unroll
  for (int i = 0; i < 4; ++i) {
    int kr = r + i * 8;
    tile[kr][c] = W[(size_t)(k0 + kr) * EMB + n0 + c];
  }
  __syncthreads();
#pragma unroll
  for (int i = 0; i < 4; ++i) {
    int nr = r + i * 8;
    float x = tile[c][nr];           // k = k0+c, n = n0+nr
    unsigned short hi = f2bf(x);
    unsigned short lo = f2bf(x - bf2f(hi));
    wth[(size_t)(n0 + nr) * HIDDEN + k0 + c] = hi;
    wtl[(size_t)(n0 + nr) * HIDDEN + k0 + c] = lo;
  }
}

// ---------------------------------------------------------------------------
// Kernel 1: pe[v] = normalize(emb[v] @ W + b) via bf16x3-split MFMA.
// 477 blocks x 64 rows; 4 waves (2m x 2n), wave tile 32x64, 16x16x32 bf16.
// LDS tiles stride 72 bf16 (144 B) -> conflict-free-ish ds_read_b128.
// ---------------------------------------------------------------------------
__global__ __launch_bounds__(256) void colbert_proj_mfma(
    const float* __restrict__ emb, const unsigned short* __restrict__ wth,
    const unsigned short* __restrict__ wtl, const float* __restrict__ bias,
    float* __restrict__ pe) {
  __shared__ __align__(16) char smem[55296];
  unsigned short* Ah = (unsigned short*)smem;   // [64][72]
  unsigned short* Al = Ah + 64 * 72;            // [64][72]
  unsigned short* Wh = Al + 64 * 72;            // [128][72]
  unsigned short* Wl = Wh + 128 * 72;           // [128][72]

  const int tid  = threadIdx.x;
  const int lane = tid & 63;
  const int wid  = tid >> 6;
  const int wm   = wid & 1;       // row half (0: rows 0-31, 1: 32-63)
  const int wn   = wid >> 1;      // col half (0: n 0-63, 1: 64-127)
  const int lr   = lane & 15;
  const int kq   = lane >> 4;     // 0..3
  const int row0 = blockIdx.x * 64;

  f32x4 acc[2][4];
#pragma unroll
  for (int mi = 0; mi < 2; ++mi)
#pragma unroll
    for (int ni = 0; ni < 4; ++ni) acc[mi][ni] = (f32x4)0.f;

  for (int hc = 0; hc < HIDDEN / 64; ++hc) {
    __syncthreads();
    // stage A: 64 rows x 64 k fp32 -> split bf16 hi/lo
#pragma unroll
    for (int i = 0; i < 4; ++i) {
      int idx = i * 256 + tid;            // < 1024
      int row = idx >> 4, c4 = idx & 15;
      int gr = row0 + row; if (gr > VOCAB - 1) gr = VOCAB - 1;
      float4 v = *(const float4*)(emb + (size_t)gr * HIDDEN + hc * 64 + c4 * 4);
      float xs[4] = {v.x, v.y, v.z, v.w};
      ushort4 hh, ll;
      unsigned short* hp = (unsigned short*)&hh;
      unsigned short* lp = (unsigned short*)&ll;
#pragma unroll
      for (int j = 0; j < 4; ++j) {
        hp[j] = f2bf(xs[j]);
        lp[j] = f2bf(xs[j] - bf2f(hp[j]));
      }
      *(ushort4*)&Ah[row * 72 + c4 * 4] = hh;
      *(ushort4*)&Al[row * 72 + c4 * 4] = ll;
    }
    // stage W^T hi/lo: 128 n x 64 k bf16, plain b128 copies
#pragma unroll
    for (int i = 0; i < 4; ++i) {
      int idx = i * 256 + tid;            // < 1024
      int n = idx >> 3, k8 = idx & 7;
      size_t src = (size_t)n * HIDDEN + hc * 64 + k8 * 8;
      *(uint4*)&Wh[n * 72 + k8 * 8] = *(const uint4*)(wth + src);
      *(uint4*)&Wl[n * 72 + k8 * 8] = *(const uint4*)(wtl + src);
    }
    __syncthreads();

#pragma unroll
    for (int kk = 0; kk < 2; ++kk) {
      const int ko = kk * 32 + kq * 8;
      bf16x8 ah[2], al[2], bh[4], bl[4];
#pragma unroll
      for (int mi = 0; mi < 2; ++mi) {
        int r = wm * 32 + mi * 16 + lr;
        ah[mi] = *(bf16x8*)&Ah[r * 72 + ko];
        al[mi] = *(bf16x8*)&Al[r * 72 + ko];
      }
#pragma unroll
      for (int ni = 0; ni < 4; ++ni) {
        int n = wn * 64 + ni * 16 + lr;
        bh[ni] = *(bf16x8*)&Wh[n * 72 + ko];
        bl[ni] = *(bf16x8*)&Wl[n * 72 + ko];
      }
#pragma unroll
      for (int mi = 0; mi < 2; ++mi)
#pragma unroll
        for (int ni = 0; ni < 4; ++ni) {
          acc[mi][ni] = __builtin_amdgcn_mfma_f32_16x16x32_bf16(ah[mi], bh[ni], acc[mi][ni], 0, 0, 0);
          acc[mi][ni] = __builtin_amdgcn_mfma_f32_16x16x32_bf16(ah[mi], bl[ni], acc[mi][ni], 0, 0, 0);
          acc[mi][ni] = __builtin_amdgcn_mfma_f32_16x16x32_bf16(al[mi], bh[ni], acc[mi][ni], 0, 0, 0);
        }
    }
  }

  // epilogue: bias + L2-normalize. Reuse LDS as fp32 [64][132].
  __syncthreads();
  float* ep = (float*)smem;
#pragma unroll
  for (int ni = 0; ni < 4; ++ni) {
    int col = wn * 64 + ni * 16 + lr;
    float bb = bias[col];
#pragma unroll
    for (int mi = 0; mi < 2; ++mi)
#pragma unroll
      for (int j = 0; j < 4; ++j) {
        int r = wm * 32 + mi * 16 + kq * 4 + j;   // C layout: row=(lane>>4)*4+j, col=lane&15
        ep[r * 132 + col] = acc[mi][ni][j] + bb;
      }
  }
  __syncthreads();
  {
    int row = tid >> 2, quad = tid & 3;
    float4 vv[8];
    float ss = 0.f;
#pragma unroll
    for (int i = 0; i < 8; ++i) {
      vv[i] = *(float4*)&ep[row * 132 + quad * 32 + i * 4];
      ss += vv[i].x * vv[i].x + vv[i].y * vv[i].y + vv[i].z * vv[i].z + vv[i].w * vv[i].w;
    }
    ss += __shfl_xor(ss, 1);
    ss += __shfl_xor(ss, 2);
    float sc = 1.f / (sqrtf(ss) + 1e-12f);
    int gr = row0 + row;
    if (gr < VOCAB) {
      float4* dst = (float4*)(pe + (size_t)gr * EMB + quad * 32);
#pragma unroll
      for (int i = 0; i < 8; ++i)
        dst[i] = make_float4(vv[i].x * sc, vv[i].y * sc, vv[i].z * sc, vv[i].w * sc);
    }
  }
}

// ---------------------------------------------------------------------------
// Kernel 2: per-batch MaxSim score (unchanged from R0).
// ---------------------------------------------------------------------------
__global__ __launch_bounds__(256) void colbert_score(
    const int* __restrict__ qids, const int* __restrict__ qmask,
    const int* __restrict__ dids, const int* __restrict__ dmask,
    const float* __restrict__ pe, float* __restrict__ out) {
  __shared__ float4 qs4[32 * 32];  // [q=32][k4=32]  16 KB
  __shared__ float4 ds4[64 * 32];  // [t=64][slot=32] 32 KB (swizzled)
  __shared__ float partial[8];

  const int b   = blockIdx.x;
  const int tid = threadIdx.x;
  const int tc  = tid & 31;
  const int tq  = tid >> 5;

#pragma unroll
  for (int i = 0; i < 4; ++i) {
    int idx = i * 256 + tid;
    int qrow = idx >> 5, c4 = idx & 31;
    int qid = qids[b * QLEN + qrow];
    qs4[idx] = ((const float4*)pe)[(size_t)qid * 32 + c4];
  }

  float maxv[4] = {-3.0e38f, -3.0e38f, -3.0e38f, -3.0e38f};

  for (int tile = 0; tile < 3; ++tile) {
    __syncthreads();
#pragma unroll
    for (int i = 0; i < 8; ++i) {
      int idx = i * 256 + tid;
      int tl = idx >> 5, c4 = idx & 31;
      int t = tile * 64 + tl;
      int did = dids[b * DLEN + (t < DLEN ? t : DLEN - 1)];
      ds4[tl * 32 + ((c4 + tl) & 31)] = ((const float4*)pe)[(size_t)did * 32 + c4];
    }
    __syncthreads();

    float dots[2][4];
#pragma unroll
    for (int j = 0; j < 2; ++j)
#pragma unroll
      for (int r = 0; r < 4; ++r) dots[j][r] = 0.f;

#pragma unroll 4
    for (int k4 = 0; k4 < 32; ++k4) {
      int slot = (k4 + tc) & 31;
      float4 d0 = ds4[tc * 32 + slot];
      float4 d1 = ds4[(tc + 32) * 32 + slot];
#pragma unroll
      for (int r = 0; r < 4; ++r) {
        float4 q = qs4[(tq * 4 + r) * 32 + k4];
        dots[0][r] += q.x * d0.x + q.y * d0.y + q.z * d0.z + q.w * d0.w;
        dots[1][r] += q.x * d1.x + q.y * d1.y + q.z * d1.z + q.w * d1.w;
      }
    }

#pragma unroll
    for (int j = 0; j < 2; ++j) {
      int t = tile * 64 + tc + 32 * j;
      if (t < DLEN) {
        int m = dmask[b * DLEN + t];
#pragma unroll
        for (int r = 0; r < 4; ++r) {
          float s = (m > 0) ? dots[j][r] : NEGV;
          maxv[r] = fmaxf(maxv[r], s);
        }
      }
    }
  }

#pragma unroll
  for (int r = 0; r < 4; ++r)
#pragma unroll
    for (int m = 16; m >= 1; m >>= 1)
      maxv[r] = fmaxf(maxv[r], __shfl_xor(maxv[r], m));

  if (tc == 0) {
    float s = 0.f;
#pragma unroll
    for (int r = 0; r < 4; ++r)
      s += maxv[r] * (float)qmask[b * QLEN + tq * 4 + r];
    partial[tq] = s;
  }
  __syncthreads();
  if (tid == 0) {
    float s = 0.f;
#pragma unroll
    for (int i = 0; i < 8; ++i) s += partial[i];
    out[b] = s;
  }
}

// ---------------------------------------------------------------------------
extern "C" void kernel_launch(void* const* d_in, const int* in_sizes, int n_in,
                              void* d_out, int out_size, void* d_ws, size_t ws_size,
                              hipStream_t stream) {
  const int*   qids  = (const int*)d_in[0];
  const int*   qmask = (const int*)d_in[1];
  const int*   dids  = (const int*)d_in[2];
  const int*   dmask = (const int*)d_in[3];
  const float* emb   = (const float*)d_in[4];
  const float* W     = (const float*)d_in[5];
  const float* bias  = (const float*)d_in[6];
  float*       out   = (float*)d_out;

  char* ws = (char*)d_ws;
  float* pe = (float*)ws;                                   // 15,627,264 B
  unsigned short* wth = (unsigned short*)(ws + 15627264);   //    196,608 B
  unsigned short* wtl = (unsigned short*)(ws + 15627264 + 196608);

  prep_wt<<<dim3(HIDDEN / 32, EMB / 32), 256, 0, stream>>>(W, wth, wtl);
  colbert_proj_mfma<<<(VOCAB + 63) / 64, 256, 0, stream>>>(emb, wth, wtl, bias, pe);
  colbert_score<<<BATCH, 256, 0, stream>>>(qids, qmask, dids, dmask, pe, out);
}

// Round 3
// 51.033 us; speedup vs baseline: 2.7490x; 1.6308x over previous
//
#include <hip/hip_runtime.h>
#include <math.h>

#define VOCAB  30522
#define HIDDEN 768
#define EMB    128
#define BATCH  1024
#define QLEN   32
#define DLEN   180
#define NEGV   (-1e4f)

typedef __attribute__((ext_vector_type(8))) short bf16x8;
typedef __attribute__((ext_vector_type(4))) float f32x4;

__device__ __forceinline__ unsigned short f2bf(float x) {
  union { float f; unsigned u; } v; v.f = x;
  unsigned r = v.u + 0x7FFFu + ((v.u >> 16) & 1u);
  return (unsigned short)(r >> 16);
}
__device__ __forceinline__ float bf2f(unsigned short h) {
  union { float f; unsigned u; } v; v.u = ((unsigned)h) << 16;
  return v.f;
}

// ---------------------------------------------------------------------------
// Kernel 0: W [768][128] fp32  ->  WT_hi / WT_lo  bf16 [128][768] (split).
// ---------------------------------------------------------------------------
__global__ __launch_bounds__(256) void prep_wt(
    const float* __restrict__ W, unsigned short* __restrict__ wth,
    unsigned short* __restrict__ wtl) {
  __shared__ float tile[32][33];
  const int k0 = blockIdx.x * 32, n0 = blockIdx.y * 32;
  const int t = threadIdx.x, r = t >> 5, c = t & 31;
#pragma unroll
  for (int i = 0; i < 4; ++i) {
    int kr = r + i * 8;
    tile[kr][c] = W[(size_t)(k0 + kr) * EMB + n0 + c];
  }
  __syncthreads();
#pragma unroll
  for (int i = 0; i < 4; ++i) {
    int nr = r + i * 8;
    float x = tile[c][nr];           // k = k0+c, n = n0+nr
    unsigned short hi = f2bf(x);
    unsigned short lo = f2bf(x - bf2f(hi));
    wth[(size_t)(n0 + nr) * HIDDEN + k0 + c] = hi;
    wtl[(size_t)(n0 + nr) * HIDDEN + k0 + c] = lo;
  }
}

// ---------------------------------------------------------------------------
// Kernel 1: pebf[v] = bf16(normalize(emb[v] @ W + b)) via bf16x3-split MFMA.
// 477 blocks x 64 rows; 4 waves (2m x 2n), wave tile 32x64, 16x16x32 bf16.
// ---------------------------------------------------------------------------
__global__ __launch_bounds__(256) void colbert_proj_mfma(
    const float* __restrict__ emb, const unsigned short* __restrict__ wth,
    const unsigned short* __restrict__ wtl, const float* __restrict__ bias,
    unsigned short* __restrict__ pebf) {
  __shared__ __align__(16) char smem[55296];
  unsigned short* Ah = (unsigned short*)smem;   // [64][72]
  unsigned short* Al = Ah + 64 * 72;            // [64][72]
  unsigned short* Wh = Al + 64 * 72;            // [128][72]
  unsigned short* Wl = Wh + 128 * 72;           // [128][72]

  const int tid  = threadIdx.x;
  const int lane = tid & 63;
  const int wid  = tid >> 6;
  const int wm   = wid & 1;
  const int wn   = wid >> 1;
  const int lr   = lane & 15;
  const int kq   = lane >> 4;
  const int row0 = blockIdx.x * 64;

  f32x4 acc[2][4];
#pragma unroll
  for (int mi = 0; mi < 2; ++mi)
#pragma unroll
    for (int ni = 0; ni < 4; ++ni) acc[mi][ni] = (f32x4)0.f;

  for (int hc = 0; hc < HIDDEN / 64; ++hc) {
    __syncthreads();
#pragma unroll
    for (int i = 0; i < 4; ++i) {
      int idx = i * 256 + tid;            // < 1024
      int row = idx >> 4, c4 = idx & 15;
      int gr = row0 + row; if (gr > VOCAB - 1) gr = VOCAB - 1;
      float4 v = *(const float4*)(emb + (size_t)gr * HIDDEN + hc * 64 + c4 * 4);
      float xs[4] = {v.x, v.y, v.z, v.w};
      ushort4 hh, ll;
      unsigned short* hp = (unsigned short*)&hh;
      unsigned short* lp = (unsigned short*)&ll;
#pragma unroll
      for (int j = 0; j < 4; ++j) {
        hp[j] = f2bf(xs[j]);
        lp[j] = f2bf(xs[j] - bf2f(hp[j]));
      }
      *(ushort4*)&Ah[row * 72 + c4 * 4] = hh;
      *(ushort4*)&Al[row * 72 + c4 * 4] = ll;
    }
#pragma unroll
    for (int i = 0; i < 4; ++i) {
      int idx = i * 256 + tid;            // < 1024
      int n = idx >> 3, k8 = idx & 7;
      size_t src = (size_t)n * HIDDEN + hc * 64 + k8 * 8;
      *(uint4*)&Wh[n * 72 + k8 * 8] = *(const uint4*)(wth + src);
      *(uint4*)&Wl[n * 72 + k8 * 8] = *(const uint4*)(wtl + src);
    }
    __syncthreads();

#pragma unroll
    for (int kk = 0; kk < 2; ++kk) {
      const int ko = kk * 32 + kq * 8;
      bf16x8 ah[2], al[2], bh[4], bl[4];
#pragma unroll
      for (int mi = 0; mi < 2; ++mi) {
        int r = wm * 32 + mi * 16 + lr;
        ah[mi] = *(bf16x8*)&Ah[r * 72 + ko];
        al[mi] = *(bf16x8*)&Al[r * 72 + ko];
      }
#pragma unroll
      for (int ni = 0; ni < 4; ++ni) {
        int n = wn * 64 + ni * 16 + lr;
        bh[ni] = *(bf16x8*)&Wh[n * 72 + ko];
        bl[ni] = *(bf16x8*)&Wl[n * 72 + ko];
      }
#pragma unroll
      for (int mi = 0; mi < 2; ++mi)
#pragma unroll
        for (int ni = 0; ni < 4; ++ni) {
          acc[mi][ni] = __builtin_amdgcn_mfma_f32_16x16x32_bf16(ah[mi], bh[ni], acc[mi][ni], 0, 0, 0);
          acc[mi][ni] = __builtin_amdgcn_mfma_f32_16x16x32_bf16(ah[mi], bl[ni], acc[mi][ni], 0, 0, 0);
          acc[mi][ni] = __builtin_amdgcn_mfma_f32_16x16x32_bf16(al[mi], bh[ni], acc[mi][ni], 0, 0, 0);
        }
    }
  }

  // epilogue: bias + L2-normalize -> bf16. Reuse LDS as fp32 [64][132].
  __syncthreads();
  float* ep = (float*)smem;
#pragma unroll
  for (int ni = 0; ni < 4; ++ni) {
    int col = wn * 64 + ni * 16 + lr;
    float bb = bias[col];
#pragma unroll
    for (int mi = 0; mi < 2; ++mi)
#pragma unroll
      for (int j = 0; j < 4; ++j) {
        int r = wm * 32 + mi * 16 + kq * 4 + j;
        ep[r * 132 + col] = acc[mi][ni][j] + bb;
      }
  }
  __syncthreads();
  {
    int row = tid >> 2, quad = tid & 3;
    float4 vv[8];
    float ss = 0.f;
#pragma unroll
    for (int i = 0; i < 8; ++i) {
      vv[i] = *(float4*)&ep[row * 132 + quad * 32 + i * 4];
      ss += vv[i].x * vv[i].x + vv[i].y * vv[i].y + vv[i].z * vv[i].z + vv[i].w * vv[i].w;
    }
    ss += __shfl_xor(ss, 1);
    ss += __shfl_xor(ss, 2);
    float sc = 1.f / (sqrtf(ss) + 1e-12f);
    int gr = row0 + row;
    if (gr < VOCAB) {
#pragma unroll
      for (int i = 0; i < 8; ++i) {
        ushort4 o;
        o.x = f2bf(vv[i].x * sc); o.y = f2bf(vv[i].y * sc);
        o.z = f2bf(vv[i].z * sc); o.w = f2bf(vv[i].w * sc);
        *(ushort4*)&pebf[(size_t)gr * EMB + quad * 32 + i * 4] = o;
      }
    }
  }
}

// ---------------------------------------------------------------------------
// Kernel 2: per-batch MaxSim via MFMA, fragments gathered straight from the
// L2/L3-resident bf16 table (no data staging). One block = one batch.
// sim = q(32x128) @ dT(128x192pad); wave w owns doc cols w*48..w*48+47.
// ---------------------------------------------------------------------------
__global__ __launch_bounds__(256) void colbert_score_mfma(
    const int* __restrict__ qids, const int* __restrict__ qmask,
    const int* __restrict__ dids, const int* __restrict__ dmask,
    const unsigned short* __restrict__ pebf, float* __restrict__ out) {
  __shared__ int sqid[32];
  __shared__ int sdid[192];
  __shared__ unsigned char smsk[192];
  __shared__ float wmax[4][32];

  const int b    = blockIdx.x;
  const int tid  = threadIdx.x;
  const int lane = tid & 63;
  const int wid  = tid >> 6;
  const int lr   = lane & 15;    // fragment row/col index
  const int kq   = lane >> 4;    // k-quad

  if (tid < 32) sqid[tid] = qids[b * QLEN + tid];
  if (tid < 192) {
    if (tid < DLEN) {
      sdid[tid] = dids[b * DLEN + tid];
      smsk[tid] = (unsigned char)(dmask[b * DLEN + tid] > 0 ? 1 : 0);
    } else {
      sdid[tid] = 0;
      smsk[tid] = 0;
    }
  }
  __syncthreads();

  // A fragments: q rows (shared across waves' n-tiles)
  bf16x8 af[2][4];
#pragma unroll
  for (int mi = 0; mi < 2; ++mi) {
    size_t base = (size_t)sqid[mi * 16 + lr] * EMB + kq * 8;
#pragma unroll
    for (int ks = 0; ks < 4; ++ks)
      af[mi][ks] = *(const bf16x8*)(pebf + base + ks * 32);
  }
  // B fragments: doc rows for this wave's 3 n-tiles
  const int n0 = wid * 48;
  bf16x8 bf[3][4];
#pragma unroll
  for (int ni = 0; ni < 3; ++ni) {
    size_t base = (size_t)sdid[n0 + ni * 16 + lr] * EMB + kq * 8;
#pragma unroll
    for (int ks = 0; ks < 4; ++ks)
      bf[ni][ks] = *(const bf16x8*)(pebf + base + ks * 32);
  }

  f32x4 acc[2][3];
#pragma unroll
  for (int mi = 0; mi < 2; ++mi)
#pragma unroll
    for (int ni = 0; ni < 3; ++ni) acc[mi][ni] = (f32x4)0.f;

#pragma unroll
  for (int ks = 0; ks < 4; ++ks)
#pragma unroll
    for (int mi = 0; mi < 2; ++mi)
#pragma unroll
      for (int ni = 0; ni < 3; ++ni)
        acc[mi][ni] = __builtin_amdgcn_mfma_f32_16x16x32_bf16(af[mi][ks], bf[ni][ks], acc[mi][ni], 0, 0, 0);

  // masked max over this wave's 48 doc cols. C layout: col=lane&15, row=(lane>>4)*4+j
#pragma unroll
  for (int mi = 0; mi < 2; ++mi) {
#pragma unroll
    for (int j = 0; j < 4; ++j) {
      float m = -3.0e38f;
#pragma unroll
      for (int ni = 0; ni < 3; ++ni) {
        int t = n0 + ni * 16 + lr;
        float s = smsk[t] ? acc[mi][ni][j] : NEGV;
        m = fmaxf(m, s);
      }
#pragma unroll
      for (int x = 1; x < 16; x <<= 1) m = fmaxf(m, __shfl_xor(m, x));
      if (lr == 0) wmax[wid][mi * 16 + kq * 4 + j] = m;
    }
  }
  __syncthreads();

  if (tid < 32) {
    float m = fmaxf(fmaxf(wmax[0][tid], wmax[1][tid]),
                    fmaxf(wmax[2][tid], wmax[3][tid]));
    float s = m * (float)qmask[b * QLEN + tid];
#pragma unroll
    for (int x = 1; x < 32; x <<= 1) s += __shfl_xor(s, x);
    if (tid == 0) out[b] = s;
  }
}

// ---------------------------------------------------------------------------
extern "C" void kernel_launch(void* const* d_in, const int* in_sizes, int n_in,
                              void* d_out, int out_size, void* d_ws, size_t ws_size,
                              hipStream_t stream) {
  const int*   qids  = (const int*)d_in[0];
  const int*   qmask = (const int*)d_in[1];
  const int*   dids  = (const int*)d_in[2];
  const int*   dmask = (const int*)d_in[3];
  const float* emb   = (const float*)d_in[4];
  const float* W     = (const float*)d_in[5];
  const float* bias  = (const float*)d_in[6];
  float*       out   = (float*)d_out;

  char* ws = (char*)d_ws;
  unsigned short* pebf = (unsigned short*)ws;                 // 7,813,632 B
  unsigned short* wth  = (unsigned short*)(ws + 7813632);     //   196,608 B
  unsigned short* wtl  = (unsigned short*)(ws + 7813632 + 196608);

  prep_wt<<<dim3(HIDDEN / 32, EMB / 32), 256, 0, stream>>>(W, wth, wtl);
  colbert_proj_mfma<<<(VOCAB + 63) / 64, 256, 0, stream>>>(emb, wth, wtl, bias, pebf);
  colbert_score_mfma<<<BATCH, 256, 0, stream>>>(qids, qmask, dids, dmask, pebf, out);
}

// Round 4
// 48.961 us; speedup vs baseline: 2.8653x; 1.0423x over previous
//
#include <hip/hip_runtime.h>
#include <math.h>

#define VOCAB  30522
#define HIDDEN 768
#define EMB    128
#define BATCH  1024
#define QLEN   32
#define DLEN   180
#define NEGV   (-1e4f)

typedef __attribute__((ext_vector_type(8))) short bf16x8;
typedef __attribute__((ext_vector_type(4))) float f32x4;

__device__ __forceinline__ unsigned short f2bf(float x) {
  union { float f; unsigned u; } v; v.f = x;
  unsigned r = v.u + 0x7FFFu + ((v.u >> 16) & 1u);
  return (unsigned short)(r >> 16);
}
__device__ __forceinline__ float bf2f(unsigned short h) {
  union { float f; unsigned u; } v; v.u = ((unsigned)h) << 16;
  return v.f;
}
// split 2 fp32 -> packed bf16 hi pair + packed bf16 lo pair (3 VALU/elem)
__device__ __forceinline__ void split_pk(float x0, float x1, unsigned& h, unsigned& l) {
  asm("v_cvt_pk_bf16_f32 %0, %1, %2" : "=v"(h) : "v"(x0), "v"(x1));
  float h0, h1;
  h0 = __uint_as_float(h << 16);
  h1 = __uint_as_float(h & 0xffff0000u);
  float l0 = x0 - h0, l1 = x1 - h1;
  asm("v_cvt_pk_bf16_f32 %0, %1, %2" : "=v"(l) : "v"(l0), "v"(l1));
}

// ---------------------------------------------------------------------------
// Kernel 0: W [768][128] fp32 -> fragment-major bf16 hi/lo tables.
// wf[(kk*8 + nt)*64 + lane][j]  (j=0..7 contiguous) holds
//   W[kk*32 + (lane>>4)*8 + j][nt*16 + (lane&15)]
// i.e. exactly the 16x16x32 B-fragment each lane needs: one 16B load/lane.
// ---------------------------------------------------------------------------
__global__ __launch_bounds__(256) void prep_wfrag(
    const float* __restrict__ W, unsigned short* __restrict__ wfh,
    unsigned short* __restrict__ wfl) {
  int g = blockIdx.x * 256 + threadIdx.x;   // 0..12287
  if (g >= 24 * 8 * 64) return;
  int lane = g & 63, nt = (g >> 6) & 7, kk = g >> 9;
  int lr = lane & 15, kq = lane >> 4;
  int n = nt * 16 + lr;
  int k0 = kk * 32 + kq * 8;
  unsigned short hh[8], ll[8];
#pragma unroll
  for (int j = 0; j < 8; ++j) {
    float x = W[(size_t)(k0 + j) * EMB + n];
    unsigned short hi = f2bf(x);
    hh[j] = hi;
    ll[j] = f2bf(x - bf2f(hi));
  }
  size_t base = (size_t)g * 8;
#pragma unroll
  for (int j = 0; j < 2; ++j) {
    *(ushort4*)(wfh + base + j * 4) = *(ushort4*)(hh + j * 4);
    *(ushort4*)(wfl + base + j * 4) = *(ushort4*)(ll + j * 4);
  }
}

// ---------------------------------------------------------------------------
// Kernel 1: pebf[v] = bf16(normalize(emb[v] @ W + b)), bf16x3-split MFMA.
// 477 blocks x 64 rows; 4 waves (2m x 2n), wave tile 32x64.
// A: double-buffered LDS (2 x 16 KB), XOR-swizzled, reg-staged split,
//    ONE barrier per K-chunk. B: straight from L2-resident fragment table.
// ---------------------------------------------------------------------------
__global__ __launch_bounds__(256) void colbert_proj_mfma(
    const float* __restrict__ emb, const unsigned short* __restrict__ wfh,
    const unsigned short* __restrict__ wfl, const float* __restrict__ bias,
    unsigned short* __restrict__ pebf) {
  __shared__ __align__(16) char smem[34816];  // 2 bufs x (Ah 8K + Al 8K); epi 33.8K

  const int tid  = threadIdx.x;
  const int lane = tid & 63;
  const int wid  = tid >> 6;
  const int wm   = wid & 1;
  const int wn   = wid >> 1;
  const int lr   = lane & 15;
  const int kq   = lane >> 4;
  const int row0 = blockIdx.x * 64;

  const int srow = tid >> 4;   // staging: row group base (0..15)
  const int sc4  = tid & 15;   // staging: float4 index within 64-float row

  f32x4 acc[2][4];
#pragma unroll
  for (int mi = 0; mi < 2; ++mi)
#pragma unroll
    for (int ni = 0; ni < 4; ++ni) acc[mi][ni] = (f32x4)0.f;

  float4 ar[4];
#pragma unroll
  for (int i = 0; i < 4; ++i) {
    int row = i * 16 + srow;
    int gr = row0 + row; if (gr > VOCAB - 1) gr = VOCAB - 1;
    ar[i] = *(const float4*)(emb + (size_t)gr * HIDDEN + sc4 * 4);
  }

#define WRITE_A(bufidx)                                                        \
  {                                                                            \
    char* Ahb = smem + (bufidx) * 16384;                                       \
    char* Alb = Ahb + 8192;                                                    \
    _Pragma("unroll")                                                          \
    for (int i = 0; i < 4; ++i) {                                              \
      int row = i * 16 + srow;                                                 \
      unsigned h0, l0, h1, l1;                                                 \
      split_pk(ar[i].x, ar[i].y, h0, l0);                                      \
      split_pk(ar[i].z, ar[i].w, h1, l1);                                      \
      int byt = (row * 128 + sc4 * 8) ^ ((row & 7) << 4);                      \
      *(uint2*)(Ahb + byt) = make_uint2(h0, h1);                               \
      *(uint2*)(Alb + byt) = make_uint2(l0, l1);                               \
    }                                                                          \
  }

  WRITE_A(0);
  __syncthreads();

  for (int hc = 0; hc < 12; ++hc) {
    const int cur = hc & 1;
    // prefetch next A chunk into registers (latency hides under MFMA below)
    if (hc < 11) {
#pragma unroll
      for (int i = 0; i < 4; ++i) {
        int row = i * 16 + srow;
        int gr = row0 + row; if (gr > VOCAB - 1) gr = VOCAB - 1;
        ar[i] = *(const float4*)(emb + (size_t)gr * HIDDEN + (hc + 1) * 64 + sc4 * 4);
      }
    }
    char* Ahb = smem + cur * 16384;
    char* Alb = Ahb + 8192;
#pragma unroll
    for (int kk = 0; kk < 2; ++kk) {
      // B fragments straight from global (L2-resident, coalesced 1KB/wave)
      bf16x8 bh[4], bl[4];
      size_t bbase = ((size_t)((hc * 2 + kk) * 8 + wn * 4) * 64 + lane) * 8;
#pragma unroll
      for (int ni = 0; ni < 4; ++ni) {
        bh[ni] = *(const bf16x8*)(wfh + bbase + ni * 512);
        bl[ni] = *(const bf16x8*)(wfl + bbase + ni * 512);
      }
      // A fragments from swizzled LDS
      bf16x8 ah[2], al[2];
#pragma unroll
      for (int mi = 0; mi < 2; ++mi) {
        int row = wm * 32 + mi * 16 + lr;
        int byt = (row * 128 + kk * 64 + kq * 16) ^ ((row & 7) << 4);
        ah[mi] = *(bf16x8*)(Ahb + byt);
        al[mi] = *(bf16x8*)(Alb + byt);
      }
#pragma unroll
      for (int mi = 0; mi < 2; ++mi)
#pragma unroll
        for (int ni = 0; ni < 4; ++ni) {
          acc[mi][ni] = __builtin_amdgcn_mfma_f32_16x16x32_bf16(ah[mi], bh[ni], acc[mi][ni], 0, 0, 0);
          acc[mi][ni] = __builtin_amdgcn_mfma_f32_16x16x32_bf16(ah[mi], bl[ni], acc[mi][ni], 0, 0, 0);
          acc[mi][ni] = __builtin_amdgcn_mfma_f32_16x16x32_bf16(al[mi], bh[ni], acc[mi][ni], 0, 0, 0);
        }
    }
    if (hc < 11) WRITE_A(cur ^ 1);
    __syncthreads();   // one barrier per chunk
  }

  // epilogue: bias + L2-normalize -> bf16. Reuse LDS as fp32 [64][132].
  float* ep = (float*)smem;
#pragma unroll
  for (int ni = 0; ni < 4; ++ni) {
    int col = wn * 64 + ni * 16 + lr;
    float bb = bias[col];
#pragma unroll
    for (int mi = 0; mi < 2; ++mi)
#pragma unroll
      for (int j = 0; j < 4; ++j) {
        int r = wm * 32 + mi * 16 + kq * 4 + j;   // C: col=lane&15, row=(lane>>4)*4+j
        ep[r * 132 + col] = acc[mi][ni][j] + bb;
      }
  }
  __syncthreads();
  {
    int row = tid >> 2, quad = tid & 3;
    float4 vv[8];
    float ss = 0.f;
#pragma unroll
    for (int i = 0; i < 8; ++i) {
      vv[i] = *(float4*)&ep[row * 132 + quad * 32 + i * 4];
      ss += vv[i].x * vv[i].x + vv[i].y * vv[i].y + vv[i].z * vv[i].z + vv[i].w * vv[i].w;
    }
    ss += __shfl_xor(ss, 1);
    ss += __shfl_xor(ss, 2);
    float sc = 1.f / (sqrtf(ss) + 1e-12f);
    int gr = row0 + row;
    if (gr < VOCAB) {
#pragma unroll
      for (int i = 0; i < 8; ++i) {
        ushort4 o;
        o.x = f2bf(vv[i].x * sc); o.y = f2bf(vv[i].y * sc);
        o.z = f2bf(vv[i].z * sc); o.w = f2bf(vv[i].w * sc);
        *(ushort4*)&pebf[(size_t)gr * EMB + quad * 32 + i * 4] = o;
      }
    }
  }
}

// ---------------------------------------------------------------------------
// Kernel 2: per-batch MaxSim via MFMA, fragments gathered straight from the
// L2/L3-resident bf16 table (no data staging). One block = one batch.
// ---------------------------------------------------------------------------
__global__ __launch_bounds__(256) void colbert_score_mfma(
    const int* __restrict__ qids, const int* __restrict__ qmask,
    const int* __restrict__ dids, const int* __restrict__ dmask,
    const unsigned short* __restrict__ pebf, float* __restrict__ out) {
  __shared__ int sqid[32];
  __shared__ int sdid[192];
  __shared__ unsigned char smsk[192];
  __shared__ float wmax[4][32];

  const int b    = blockIdx.x;
  const int tid  = threadIdx.x;
  const int lane = tid & 63;
  const int wid  = tid >> 6;
  const int lr   = lane & 15;
  const int kq   = lane >> 4;

  if (tid < 32) sqid[tid] = qids[b * QLEN + tid];
  if (tid < 192) {
    if (tid < DLEN) {
      sdid[tid] = dids[b * DLEN + tid];
      smsk[tid] = (unsigned char)(dmask[b * DLEN + tid] > 0 ? 1 : 0);
    } else {
      sdid[tid] = 0;
      smsk[tid] = 0;
    }
  }
  __syncthreads();

  bf16x8 af[2][4];
#pragma unroll
  for (int mi = 0; mi < 2; ++mi) {
    size_t base = (size_t)sqid[mi * 16 + lr] * EMB + kq * 8;
#pragma unroll
    for (int ks = 0; ks < 4; ++ks)
      af[mi][ks] = *(const bf16x8*)(pebf + base + ks * 32);
  }
  const int n0 = wid * 48;
  bf16x8 bf[3][4];
#pragma unroll
  for (int ni = 0; ni < 3; ++ni) {
    size_t base = (size_t)sdid[n0 + ni * 16 + lr] * EMB + kq * 8;
#pragma unroll
    for (int ks = 0; ks < 4; ++ks)
      bf[ni][ks] = *(const bf16x8*)(pebf + base + ks * 32);
  }

  f32x4 acc[2][3];
#pragma unroll
  for (int mi = 0; mi < 2; ++mi)
#pragma unroll
    for (int ni = 0; ni < 3; ++ni) acc[mi][ni] = (f32x4)0.f;

#pragma unroll
  for (int ks = 0; ks < 4; ++ks)
#pragma unroll
    for (int mi = 0; mi < 2; ++mi)
#pragma unroll
      for (int ni = 0; ni < 3; ++ni)
        acc[mi][ni] = __builtin_amdgcn_mfma_f32_16x16x32_bf16(af[mi][ks], bf[ni][ks], acc[mi][ni], 0, 0, 0);

#pragma unroll
  for (int mi = 0; mi < 2; ++mi) {
#pragma unroll
    for (int j = 0; j < 4; ++j) {
      float m = -3.0e38f;
#pragma unroll
      for (int ni = 0; ni < 3; ++ni) {
        int t = n0 + ni * 16 + lr;
        float s = smsk[t] ? acc[mi][ni][j] : NEGV;
        m = fmaxf(m, s);
      }
#pragma unroll
      for (int x = 1; x < 16; x <<= 1) m = fmaxf(m, __shfl_xor(m, x));
      if (lr == 0) wmax[wid][mi * 16 + kq * 4 + j] = m;
    }
  }
  __syncthreads();

  if (tid < 32) {
    float m = fmaxf(fmaxf(wmax[0][tid], wmax[1][tid]),
                    fmaxf(wmax[2][tid], wmax[3][tid]));
    float s = m * (float)qmask[b * QLEN + tid];
#pragma unroll
    for (int x = 1; x < 32; x <<= 1) s += __shfl_xor(s, x);
    if (tid == 0) out[b] = s;
  }
}

// ---------------------------------------------------------------------------
extern "C" void kernel_launch(void* const* d_in, const int* in_sizes, int n_in,
                              void* d_out, int out_size, void* d_ws, size_t ws_size,
                              hipStream_t stream) {
  const int*   qids  = (const int*)d_in[0];
  const int*   qmask = (const int*)d_in[1];
  const int*   dids  = (const int*)d_in[2];
  const int*   dmask = (const int*)d_in[3];
  const float* emb   = (const float*)d_in[4];
  const float* W     = (const float*)d_in[5];
  const float* bias  = (const float*)d_in[6];
  float*       out   = (float*)d_out;

  char* ws = (char*)d_ws;
  unsigned short* pebf = (unsigned short*)ws;                 // 7,813,632 B
  unsigned short* wfh  = (unsigned short*)(ws + 7813632);     //   196,608 B
  unsigned short* wfl  = (unsigned short*)(ws + 7813632 + 196608);

  prep_wfrag<<<48, 256, 0, stream>>>(W, wfh, wfl);
  colbert_proj_mfma<<<(VOCAB + 63) / 64, 256, 0, stream>>>(emb, wfh, wfl, bias, pebf);
  colbert_score_mfma<<<BATCH, 256, 0, stream>>>(qids, qmask, dids, dmask, pebf, out);
}